// Round 2
// baseline (437.308 us; speedup 1.0000x reference)
//
#include <hip/hip_runtime.h>

#define IMG 512
#define HW (IMG * IMG)
#define NB 32
#define NIMG 64
#define INF __builtin_inff()

// ---- new-path geometry: depth-2 fusion, 8-row bands ----
#define BAND 8
#define NBAND (IMG / BAND)         // 64 bands per image
#define HALO 4                      // 2 rows per iteration x 2 fused iterations
#define NSTEP (BAND + 2 * HALO)     // 16 single-row steps

// ---- fallback geometry: verified round-0 kernel (depth-5, 16-row bands) ----
#define FB_BAND 16
#define FB_NBAND (IMG / FB_BAND)            // 32
#define NSTG 5
#define FB_HALO (2 * NSTG)                  // 10
#define FB_NSTEP ((FB_BAND + 2 * FB_HALO) / 2)  // 18 row-pair steps

// DPP whole-wave shift-by-1 (CDNA keeps Vega wave_shl/shr DPP controls).
// wave_shr1: lane i gets lane i-1's value; lane 0 gets `ident`.
static __device__ __forceinline__ float dpp_from_prev(float v, float ident) {
    return __int_as_float(__builtin_amdgcn_update_dpp(
        __float_as_int(ident), __float_as_int(v), 0x138, 0xF, 0xF, false));
}
// wave_shl1: lane i gets lane i+1's value; lane 63 gets `ident`.
static __device__ __forceinline__ float dpp_from_next(float v, float ident) {
    return __int_as_float(__builtin_amdgcn_update_dpp(
        __float_as_int(ident), __float_as_int(v), 0x130, 0xF, 0xF, false));
}

// One lane owns 8 contiguous columns: a = cols[8l..8l+3], b = cols[8l+4..8l+7].
struct Row { float4 a, b; };

static __device__ __forceinline__ float min3f(float a, float b, float c) { return fminf(fminf(a, b), c); }
static __device__ __forceinline__ float max3f(float a, float b, float c) { return fmaxf(fmaxf(a, b), c); }

static __device__ __forceinline__ Row splat(float v) {
    Row r;
    r.a = make_float4(v, v, v, v);
    r.b = make_float4(v, v, v, v);
    return r;
}

static __device__ __forceinline__ Row rmin3(const Row& x, const Row& y, const Row& z) {
    Row o;
    const float* px = (const float*)&x;
    const float* py = (const float*)&y;
    const float* pz = (const float*)&z;
    float* po = (float*)&o;
#pragma unroll
    for (int i = 0; i < 8; ++i) po[i] = min3f(px[i], py[i], pz[i]);
    return o;
}

static __device__ __forceinline__ Row rmax3(const Row& x, const Row& y, const Row& z) {
    Row o;
    const float* px = (const float*)&x;
    const float* py = (const float*)&y;
    const float* pz = (const float*)&z;
    float* po = (float*)&o;
#pragma unroll
    for (int i = 0; i < 8; ++i) po[i] = max3f(px[i], py[i], pz[i]);
    return o;
}

// Horizontal 3-min across the 512-wide row. Lane-edge neighbors via DPP
// wave shifts; image edges get +inf identity for free from bound_ctrl.
static __device__ __forceinline__ Row hmin3(const Row& v) {
    float shl = dpp_from_prev(v.b.w, INF);
    float shr = dpp_from_next(v.a.x, INF);
    Row o;
    o.a.x = min3f(shl,   v.a.x, v.a.y);
    o.a.y = min3f(v.a.x, v.a.y, v.a.z);
    o.a.z = min3f(v.a.y, v.a.z, v.a.w);
    o.a.w = min3f(v.a.z, v.a.w, v.b.x);
    o.b.x = min3f(v.a.w, v.b.x, v.b.y);
    o.b.y = min3f(v.b.x, v.b.y, v.b.z);
    o.b.z = min3f(v.b.y, v.b.z, v.b.w);
    o.b.w = min3f(v.b.z, v.b.w, shr);
    return o;
}

static __device__ __forceinline__ Row hmax3(const Row& v) {
    float shl = dpp_from_prev(v.b.w, -INF);
    float shr = dpp_from_next(v.a.x, -INF);
    Row o;
    o.a.x = max3f(shl,   v.a.x, v.a.y);
    o.a.y = max3f(v.a.x, v.a.y, v.a.z);
    o.a.z = max3f(v.a.y, v.a.z, v.a.w);
    o.a.w = max3f(v.a.z, v.a.w, v.b.x);
    o.b.x = max3f(v.a.w, v.b.x, v.b.y);
    o.b.y = max3f(v.b.x, v.b.y, v.b.z);
    o.b.z = max3f(v.b.y, v.b.z, v.b.w);
    o.b.w = max3f(v.b.z, v.b.w, shr);
    return o;
}

// out = relu(x - relu(mp - mn)). For x >= 0 and the mp/mn values that reach
// consumed outputs (never both -INF) this is bit-exactly med3(0, x, x-(mp-mn)).
static __device__ __forceinline__ Row relu_out(const Row& x, const Row& mp, const Row& mn) {
    Row o;
    const float* px = (const float*)&x;
    const float* pp = (const float*)&mp;
    const float* pm = (const float*)&mn;
    float* po = (float*)&o;
#pragma unroll
    for (int i = 0; i < 8; ++i) {
        float d = pp[i] - pm[i];
        po[i] = __builtin_amdgcn_fmed3f(0.f, px[i], px[i] - d);
    }
    return o;
}

static __device__ __forceinline__ Row load_row(const float* __restrict__ p, int r, int lane) {
    if ((unsigned)r >= IMG) return splat(INF);   // uniform scalar branch
    const float4* q = (const float4*)(p + (size_t)r * IMG + lane * 8);
    Row o;
    o.a = q[0];
    o.b = q[1];
    return o;
}

// ============================ NEW PATH (depth-2) ============================
// Two fused skeletonize iterations over one 8-row band, single-row stepping,
// fully unrolled so per-k predicates fold and state rotation is pure renaming.
// Tightened trapezoid:
//   k=0,1   : seed stage-0 x-state (loads only)
//   k=2,3   : stage-0 min-side only (build mn chain)
//   k=4,5   : stage-0 full (first outs rows B-2,B-1), seed stage-1 x-state
//   k=6,7   : stage-0 full, stage-1 min-side only
//   k=8..15 : both full; stage-1 out rows B..B+7 stored / reduced
// MODE 0: store out rows to dst. MODE 1: accumulate prod/val against weights w.
template <bool EDGE, int MODE>
static __device__ __forceinline__ void run2(const float* __restrict__ src,
                                            float* __restrict__ dst,
                                            const float* __restrict__ w,
                                            int B, int lane,
                                            float& s_prod, float& s_val) {
    Row s0x2 = splat(INF), s0x1 = splat(INF), s0m2 = splat(-INF), s0m1 = splat(-INF);
    Row s1x2 = splat(INF), s1x1 = splat(INF), s1m2 = splat(-INF), s1m1 = splat(-INF);
    // depth-2 row prefetch (covers L2/L3 latency at 4 waves/SIMD)
    Row pre0 = load_row(src, B - HALO, lane);
    Row pre1 = load_row(src, B - HALO + 1, lane);
#pragma unroll
    for (int k = 0; k < NSTEP; ++k) {
        const int t = B - HALO + k;          // source row consumed this step
        Row in = pre0;
        pre0 = pre1;
        if (k < NSTEP - 2) pre1 = load_row(src, t + 2, lane);
        Row wrow;
        if (MODE == 1 && k >= 8) wrow = load_row(w, t - 4, lane);

        // ---- stage 0 (iteration A) ----
        Row out0;
        if (k >= 2) {
            Row mnew = hmin3(rmin3(s0x2, s0x1, in));        // mn[t-1]
            if (EDGE && (unsigned)(t - 1) >= IMG) mnew = splat(-INF);
            if (k >= 4) {
                Row mp = hmax3(rmax3(s0m2, s0m1, mnew));    // dilate centered t-2
                out0 = relu_out(s0x2, mp, s0m1);            // stage-0 out row t-2
                if (EDGE && (unsigned)(t - 2) >= IMG) out0 = splat(INF);
            }
            s0m2 = s0m1; s0m1 = mnew;
        }
        s0x2 = s0x1; s0x1 = in;

        // ---- stage 1 (iteration B), input row u = t-2 ----
        if (k >= 4) {
            const int u = t - 2;
            if (k >= 6) {
                Row mnew = hmin3(rmin3(s1x2, s1x1, out0));  // mn[u-1]
                if (EDGE && (unsigned)(u - 1) >= IMG) mnew = splat(-INF);
                if (k >= 8) {
                    Row mp = hmax3(rmax3(s1m2, s1m1, mnew));
                    Row out1 = relu_out(s1x2, mp, s1m1);    // final row v = u-2
                    const int v = u - 2;                    // = B + (k-8), always in-image
                    if (MODE == 0) {
                        float4* q = (float4*)(dst + (size_t)v * IMG + lane * 8);
                        q[0] = out1.a;
                        q[1] = out1.b;
                    } else {
                        const float* p = (const float*)&out1;
                        const float* qw = (const float*)&wrow;
#pragma unroll
                        for (int i = 0; i < 8; ++i) {
                            s_prod += p[i] * qw[i];
                            s_val += p[i];
                        }
                    }
                }
                s1m2 = s1m1; s1m1 = mnew;
            }
            s1x2 = s1x1; s1x1 = out0;
        }
    }
}

__global__ __launch_bounds__(64, 4) void skel2_first(const float* __restrict__ yp,
                                                     const float* __restrict__ yt,
                                                     float* __restrict__ dst) {
    const int blk = blockIdx.x;
    const int img = blk >> 6, band = blk & (NBAND - 1);
    const float* src = (img < NB) ? yp + (size_t)(2 * img + 1) * HW
                                  : yt + (size_t)(2 * (img - NB) + 1) * HW;
    float* d = dst + (size_t)img * HW;
    const int lane = threadIdx.x;
    const int B = band * BAND;
    float d0 = 0.f, d1 = 0.f;
    if (band == 0 || band == NBAND - 1) run2<true, 0>(src, d, nullptr, B, lane, d0, d1);
    else                                run2<false, 0>(src, d, nullptr, B, lane, d0, d1);
}

__global__ __launch_bounds__(64, 4) void skel2_mid(const float* __restrict__ srcb,
                                                   float* __restrict__ dstb) {
    const int blk = blockIdx.x;
    const int img = blk >> 6, band = blk & (NBAND - 1);
    const float* src = srcb + (size_t)img * HW;
    float* d = dstb + (size_t)img * HW;
    const int lane = threadIdx.x;
    const int B = band * BAND;
    float d0 = 0.f, d1 = 0.f;
    if (band == 0 || band == NBAND - 1) run2<true, 0>(src, d, nullptr, B, lane, d0, d1);
    else                                run2<false, 0>(src, d, nullptr, B, lane, d0, d1);
}

__global__ __launch_bounds__(64, 4) void skel2_last(const float* __restrict__ srcb,
                                                    const float* __restrict__ yp,
                                                    const float* __restrict__ yt,
                                                    double* __restrict__ acc) {
    const int blk = blockIdx.x;
    const int img = blk >> 6, band = blk & (NBAND - 1);
    const float* src = srcb + (size_t)img * HW;
    // skel(pred) pairs with y_true c1; skel(true) pairs with y_pred c1.
    const float* w = (img < NB) ? yt + (size_t)(2 * img + 1) * HW
                                : yp + (size_t)(2 * (img - NB) + 1) * HW;
    const int lane = threadIdx.x;
    const int B = band * BAND;

    float s_prod = 0.f, s_val = 0.f;
    if (band == 0 || band == NBAND - 1) run2<true, 1>(src, nullptr, w, B, lane, s_prod, s_val);
    else                                run2<false, 1>(src, nullptr, w, B, lane, s_prod, s_val);

#pragma unroll
    for (int off = 32; off; off >>= 1) {
        s_prod += __shfl_down(s_prod, off);
        s_val += __shfl_down(s_val, off);
    }
    if (lane == 0) {
        const int base = (img < NB) ? 0 : 2;
        atomicAdd(&acc[base], (double)s_prod);
        atomicAdd(&acc[base + 1], (double)s_val);
    }
}

// ======================= FALLBACK PATH (round-0 verified) =======================
// Row-paired skeletonize stage step. Entry state: x[0]=x[t-2], x[1]=x[t-1],
// mn[0]=mn[t-3], mn[1]=mn[t-2]. Inputs in0=x[t], in1=x[t+1]. On exit in0/in1
// hold this stage's outputs for rows (t-2, t-1), state advanced by 2 rows.
template <bool EDGE>
static __device__ __forceinline__ void step2(Row (&x)[2], Row (&mn)[2],
                                             Row& in0, Row& in1, int t) {
    Row vmin0 = rmin3(x[0], x[1], in0);      // centered row t-1
    Row vmin1 = rmin3(x[1], in0, in1);       // centered row t
    Row mna = hmin3(vmin0);                  // mn[t-1]
    Row mnb = hmin3(vmin1);                  // mn[t]
    if (EDGE) {
        if ((unsigned)(t - 1) >= IMG) mna = splat(-INF);
        if ((unsigned)t >= IMG) mnb = splat(-INF);
    }
    Row vmax0 = rmax3(mn[0], mn[1], mna);    // centered t-2
    Row vmax1 = rmax3(mn[1], mna, mnb);      // centered t-1
    Row mp0 = hmax3(vmax0);
    Row mp1 = hmax3(vmax1);
    Row out0, out1;
    {
        const float* px0 = (const float*)&x[0];
        const float* px1 = (const float*)&x[1];
        const float* pm1 = (const float*)&mn[1];
        const float* pma = (const float*)&mna;
        const float* pp0 = (const float*)&mp0;
        const float* pp1 = (const float*)&mp1;
        float* po0 = (float*)&out0;
        float* po1 = (float*)&out1;
#pragma unroll
        for (int i = 0; i < 8; ++i) {
            po0[i] = fmaxf(px0[i] - fmaxf(pp0[i] - pm1[i], 0.f), 0.f);
            po1[i] = fmaxf(px1[i] - fmaxf(pp1[i] - pma[i], 0.f), 0.f);
        }
    }
    if (EDGE) {
        if ((unsigned)(t - 2) >= IMG) out0 = splat(INF);
        if ((unsigned)(t - 1) >= IMG) out1 = splat(INF);
    }
    x[0] = in0;  x[1] = in1;
    mn[0] = mna; mn[1] = mnb;
    in0 = out0;  in1 = out1;
}

template <bool EDGE>
static __device__ __forceinline__ void run_a(const float* __restrict__ src,
                                             float* __restrict__ dst, int B, int lane) {
    Row x[NSTG][2], mn[NSTG][2];
#pragma unroll
    for (int j = 0; j < NSTG; ++j) {
        x[j][0] = splat(INF);   x[j][1] = splat(INF);
        mn[j][0] = splat(-INF); mn[j][1] = splat(-INF);
    }
    Row pre0 = load_row(src, B - FB_HALO, lane);
    Row pre1 = load_row(src, B - FB_HALO + 1, lane);
#pragma unroll 1
    for (int k = 0; k < FB_NSTEP; ++k) {
        const int t = B - FB_HALO + 2 * k;
        Row in0 = pre0, in1 = pre1;
        const int tp = (k + 1 < FB_NSTEP) ? t + 2 : -1;
        pre0 = load_row(src, tp, lane);
        pre1 = load_row(src, tp + 1, lane);
#pragma unroll
        for (int j = 0; j < NSTG; ++j)
            step2<EDGE>(x[j], mn[j], in0, in1, t - 2 * j);
        const int v = t - FB_HALO;
        if ((unsigned)(v - B) < FB_BAND) {
            float4* q0 = (float4*)(dst + (size_t)v * IMG + lane * 8);
            q0[0] = in0.a; q0[1] = in0.b;
            float4* q1 = (float4*)(dst + (size_t)(v + 1) * IMG + lane * 8);
            q1[0] = in1.a; q1[1] = in1.b;
        }
    }
}

__global__ __launch_bounds__(64, 2) void skel5_a(const float* __restrict__ yp,
                                                 const float* __restrict__ yt,
                                                 float* __restrict__ mid) {
    const int blk = blockIdx.x;
    const int img = blk >> 5, band = blk & (FB_NBAND - 1);
    const float* src = (img < NB) ? yp + (size_t)(2 * img + 1) * HW
                                  : yt + (size_t)(2 * (img - NB) + 1) * HW;
    float* dst = mid + (size_t)img * HW;
    const int lane = threadIdx.x;
    const int B = band * FB_BAND;
    if (band == 0 || band == FB_NBAND - 1) run_a<true>(src, dst, B, lane);
    else                                   run_a<false>(src, dst, B, lane);
}

template <bool EDGE>
static __device__ __forceinline__ void run_b(const float* __restrict__ src,
                                             const float* __restrict__ wp, int B, int lane,
                                             float& s_prod, float& s_val) {
    Row x[NSTG][2], mn[NSTG][2];
#pragma unroll
    for (int j = 0; j < NSTG; ++j) {
        x[j][0] = splat(INF);   x[j][1] = splat(INF);
        mn[j][0] = splat(-INF); mn[j][1] = splat(-INF);
    }
    Row pre0 = load_row(src, B - FB_HALO, lane);
    Row pre1 = load_row(src, B - FB_HALO + 1, lane);
#pragma unroll 1
    for (int k = 0; k < FB_NSTEP; ++k) {
        const int t = B - FB_HALO + 2 * k;
        Row in0 = pre0, in1 = pre1;
        const int tp = (k + 1 < FB_NSTEP) ? t + 2 : -1;
        pre0 = load_row(src, tp, lane);
        pre1 = load_row(src, tp + 1, lane);
        const int v = t - FB_HALO;
        const bool inband = (unsigned)(v - B) < FB_BAND;
        Row w0, w1;
        if (inband) {
            const float4* q0 = (const float4*)(wp + (size_t)v * IMG + lane * 8);
            w0.a = q0[0]; w0.b = q0[1];
            const float4* q1 = (const float4*)(wp + (size_t)(v + 1) * IMG + lane * 8);
            w1.a = q1[0]; w1.b = q1[1];
        }
#pragma unroll
        for (int j = 0; j < NSTG; ++j)
            step2<EDGE>(x[j], mn[j], in0, in1, t - 2 * j);
        if (inband) {
            const float* p0 = (const float*)&in0;
            const float* p1 = (const float*)&in1;
            const float* q0 = (const float*)&w0;
            const float* q1 = (const float*)&w1;
#pragma unroll
            for (int i = 0; i < 8; ++i) {
                s_prod += p0[i] * q0[i] + p1[i] * q1[i];
                s_val += p0[i] + p1[i];
            }
        }
    }
}

__global__ __launch_bounds__(64, 2) void skel5_b(const float* __restrict__ mid,
                                                 const float* __restrict__ yp,
                                                 const float* __restrict__ yt,
                                                 double* __restrict__ acc) {
    const int blk = blockIdx.x;
    const int img = blk >> 5, band = blk & (FB_NBAND - 1);
    const float* src = mid + (size_t)img * HW;
    const float* wp = (img < NB) ? yt + (size_t)(2 * img + 1) * HW
                                 : yp + (size_t)(2 * (img - NB) + 1) * HW;
    const int lane = threadIdx.x;
    const int B = band * FB_BAND;

    float s_prod = 0.f, s_val = 0.f;
    if (band == 0 || band == FB_NBAND - 1) run_b<true>(src, wp, B, lane, s_prod, s_val);
    else                                   run_b<false>(src, wp, B, lane, s_prod, s_val);

#pragma unroll
    for (int off = 32; off; off >>= 1) {
        s_prod += __shfl_down(s_prod, off);
        s_val += __shfl_down(s_val, off);
    }
    if (lane == 0) {
        const int base = (img < NB) ? 0 : 2;
        atomicAdd(&acc[base], (double)s_prod);
        atomicAdd(&acc[base + 1], (double)s_val);
    }
}

// ================================ common ================================
__global__ void finalize(const double* __restrict__ acc, float* __restrict__ out) {
    double tprec = (acc[0] + 1.0) / (acc[1] + 1.0);
    double tsens = (acc[2] + 1.0) / (acc[3] + 1.0);
    out[0] = (float)(1.0 - 2.0 * (tprec * tsens) / (tprec + tsens));
}

extern "C" void kernel_launch(void* const* d_in, const int* in_sizes, int n_in,
                              void* d_out, int out_size, void* d_ws, size_t ws_size,
                              hipStream_t stream) {
    (void)in_sizes; (void)n_in; (void)out_size;
    const float* yp = (const float*)d_in[0];
    const float* yt = (const float*)d_in[1];
    float* out = (float*)d_out;

    const size_t bufElems = (size_t)NIMG * HW;
    const size_t need2 = 2 * bufElems * sizeof(float) + 4 * sizeof(double);

    if (ws_size >= need2) {
        // New path: ping-pong skeleton buffers (2 x 64 MB) | acc (4 doubles)
        float* bufA = (float*)d_ws;
        float* bufB = bufA + bufElems;
        double* acc = (double*)(bufB + bufElems);

        hipMemsetAsync(acc, 0, 4 * sizeof(double), stream);

        const int grid = NIMG * NBAND;  // 4096 single-wave blocks = 4 waves/SIMD
        skel2_first<<<grid, 64, 0, stream>>>(yp, yt, bufA);
        skel2_mid<<<grid, 64, 0, stream>>>(bufA, bufB);
        skel2_mid<<<grid, 64, 0, stream>>>(bufB, bufA);
        skel2_mid<<<grid, 64, 0, stream>>>(bufA, bufB);
        skel2_last<<<grid, 64, 0, stream>>>(bufB, yp, yt, acc);
        finalize<<<1, 1, 0, stream>>>(acc, out);
    } else {
        // Fallback: verified round-0 structure (64 MB + 32 B workspace)
        float* mid = (float*)d_ws;
        double* acc = (double*)(mid + bufElems);

        hipMemsetAsync(acc, 0, 4 * sizeof(double), stream);

        const int grid = NIMG * FB_NBAND;  // 2048 single-wave blocks
        skel5_a<<<grid, 64, 0, stream>>>(yp, yt, mid);
        skel5_b<<<grid, 64, 0, stream>>>(mid, yp, yt, acc);
        finalize<<<1, 1, 0, stream>>>(acc, out);
    }
}

// Round 3
// 355.234 us; speedup vs baseline: 1.2310x; 1.2310x over previous
//
#include <hip/hip_runtime.h>

#define IMG 512
#define HW (IMG * IMG)
#define NB 32
#define NIMG 64
#define BAND 8
#define NBAND (IMG / BAND)              // 64 bands per image
#define NSTG 2                          // fused iterations per launch
#define HALO (2 * NSTG)                 // 4
#define NSTEP ((BAND + 2 * HALO) / 2)   // 8 row-pair steps
#define INF __builtin_inff()

// DPP whole-wave shift-by-1 (CDNA keeps Vega wave_shl/shr DPP controls).
// wave_shr1: lane i gets lane i-1's value; lane 0 gets `ident`.
static __device__ __forceinline__ float dpp_from_prev(float v, float ident) {
    return __int_as_float(__builtin_amdgcn_update_dpp(
        __float_as_int(ident), __float_as_int(v), 0x138, 0xF, 0xF, false));
}
// wave_shl1: lane i gets lane i+1's value; lane 63 gets `ident`.
static __device__ __forceinline__ float dpp_from_next(float v, float ident) {
    return __int_as_float(__builtin_amdgcn_update_dpp(
        __float_as_int(ident), __float_as_int(v), 0x130, 0xF, 0xF, false));
}

// One lane owns 8 contiguous columns: a = cols[8l..8l+3], b = cols[8l+4..8l+7].
struct Row { float4 a, b; };

static __device__ __forceinline__ float min3f(float a, float b, float c) { return fminf(fminf(a, b), c); }
static __device__ __forceinline__ float max3f(float a, float b, float c) { return fmaxf(fmaxf(a, b), c); }

static __device__ __forceinline__ Row splat(float v) {
    Row r;
    r.a = make_float4(v, v, v, v);
    r.b = make_float4(v, v, v, v);
    return r;
}

static __device__ __forceinline__ Row rmin3(const Row& x, const Row& y, const Row& z) {
    Row o;
    const float* px = (const float*)&x;
    const float* py = (const float*)&y;
    const float* pz = (const float*)&z;
    float* po = (float*)&o;
#pragma unroll
    for (int i = 0; i < 8; ++i) po[i] = min3f(px[i], py[i], pz[i]);
    return o;
}

static __device__ __forceinline__ Row rmax3(const Row& x, const Row& y, const Row& z) {
    Row o;
    const float* px = (const float*)&x;
    const float* py = (const float*)&y;
    const float* pz = (const float*)&z;
    float* po = (float*)&o;
#pragma unroll
    for (int i = 0; i < 8; ++i) po[i] = max3f(px[i], py[i], pz[i]);
    return o;
}

// Horizontal 3-min across the 512-wide row. Lane-edge neighbors via DPP
// wave shifts; image edges get +inf identity for free from bound_ctrl.
static __device__ __forceinline__ Row hmin3(const Row& v) {
    float shl = dpp_from_prev(v.b.w, INF);
    float shr = dpp_from_next(v.a.x, INF);
    Row o;
    o.a.x = min3f(shl,   v.a.x, v.a.y);
    o.a.y = min3f(v.a.x, v.a.y, v.a.z);
    o.a.z = min3f(v.a.y, v.a.z, v.a.w);
    o.a.w = min3f(v.a.z, v.a.w, v.b.x);
    o.b.x = min3f(v.a.w, v.b.x, v.b.y);
    o.b.y = min3f(v.b.x, v.b.y, v.b.z);
    o.b.z = min3f(v.b.y, v.b.z, v.b.w);
    o.b.w = min3f(v.b.z, v.b.w, shr);
    return o;
}

static __device__ __forceinline__ Row hmax3(const Row& v) {
    float shl = dpp_from_prev(v.b.w, -INF);
    float shr = dpp_from_next(v.a.x, -INF);
    Row o;
    o.a.x = max3f(shl,   v.a.x, v.a.y);
    o.a.y = max3f(v.a.x, v.a.y, v.a.z);
    o.a.z = max3f(v.a.y, v.a.z, v.a.w);
    o.a.w = max3f(v.a.z, v.a.w, v.b.x);
    o.b.x = max3f(v.a.w, v.b.x, v.b.y);
    o.b.y = max3f(v.b.x, v.b.y, v.b.z);
    o.b.z = max3f(v.b.y, v.b.z, v.b.w);
    o.b.w = max3f(v.b.z, v.b.w, shr);
    return o;
}

// out = relu(x - relu(mp - mn)). For x >= 0 on every consumed output this is
// bit-exactly med3(0, x, x - (mp - mn)): 3 ops/pixel instead of 4.
// (Verified bit-exact on-harness: round-2 run passed with absmax 0.0.)
static __device__ __forceinline__ Row relu_out(const Row& x, const Row& mp, const Row& mn) {
    Row o;
    const float* px = (const float*)&x;
    const float* pp = (const float*)&mp;
    const float* pm = (const float*)&mn;
    float* po = (float*)&o;
#pragma unroll
    for (int i = 0; i < 8; ++i) {
        float d = pp[i] - pm[i];
        po[i] = __builtin_amdgcn_fmed3f(0.f, px[i], px[i] - d);
    }
    return o;
}

static __device__ __forceinline__ Row load_row(const float* __restrict__ p, int r, int lane) {
    if ((unsigned)r >= IMG) return splat(INF);   // uniform scalar branch
    const float4* q = (const float4*)(p + (size_t)r * IMG + lane * 8);
    Row o;
    o.a = q[0];
    o.b = q[1];
    return o;
}

// Row-paired skeletonize stage step (round-0 verified structure).
// Entry state: x[0]=x[t-2], x[1]=x[t-1], mn[0]=mn[t-3], mn[1]=mn[t-2].
// Inputs in0=x[t], in1=x[t+1]. On exit in0/in1 hold this stage's outputs for
// rows (t-2, t-1), state advanced by 2 rows. Rotation is pure renaming: every
// state slot is assigned a freshly-computed value whose old copy dies here.
template <bool EDGE>
static __device__ __forceinline__ void step2(Row (&x)[2], Row (&mn)[2],
                                             Row& in0, Row& in1, int t) {
    Row vmin0 = rmin3(x[0], x[1], in0);      // centered row t-1
    Row vmin1 = rmin3(x[1], in0, in1);       // centered row t
    Row mna = hmin3(vmin0);                  // mn[t-1]
    Row mnb = hmin3(vmin1);                  // mn[t]
    if (EDGE) {
        if ((unsigned)(t - 1) >= IMG) mna = splat(-INF);
        if ((unsigned)t >= IMG) mnb = splat(-INF);
    }
    Row vmax0 = rmax3(mn[0], mn[1], mna);    // centered t-2
    Row vmax1 = rmax3(mn[1], mna, mnb);      // centered t-1
    Row mp0 = hmax3(vmax0);
    Row mp1 = hmax3(vmax1);
    Row out0 = relu_out(x[0], mp0, mn[1]);   // out row t-2
    Row out1 = relu_out(x[1], mp1, mna);     // out row t-1
    if (EDGE) {
        if ((unsigned)(t - 2) >= IMG) out0 = splat(INF);
        if ((unsigned)(t - 1) >= IMG) out1 = splat(INF);
    }
    x[0] = in0;  x[1] = in1;
    mn[0] = mna; mn[1] = mnb;
    in0 = out0;  in1 = out1;
}

// Two fused iterations over one 8-row band. #pragma unroll 1 on the k-loop is
// deliberate: full unroll lets the scheduler hoist all row loads, exploding
// register pressure into scratch spill (round-2 post-mortem: 199 MB of spill
// writes, VALUBusy 5%). Keep loads inside the rolled loop.
// MODE 0: store final rows to dst. MODE 1: reduce against weights wp.
template <bool EDGE, int MODE>
static __device__ __forceinline__ void run(const float* __restrict__ src,
                                           float* __restrict__ dst,
                                           const float* __restrict__ wp,
                                           int B, int lane,
                                           float& s_prod, float& s_val) {
    Row x[NSTG][2], mn[NSTG][2];
#pragma unroll
    for (int j = 0; j < NSTG; ++j) {
        x[j][0] = splat(INF);   x[j][1] = splat(INF);
        mn[j][0] = splat(-INF); mn[j][1] = splat(-INF);
    }
    Row pre0 = load_row(src, B - HALO, lane);
    Row pre1 = load_row(src, B - HALO + 1, lane);
#pragma unroll 1
    for (int k = 0; k < NSTEP; ++k) {
        const int t = B - HALO + 2 * k;
        Row in0 = pre0, in1 = pre1;
        const int tp = (k + 1 < NSTEP) ? t + 2 : -1;
        pre0 = load_row(src, tp, lane);
        pre1 = load_row(src, tp + 1, lane);
        const int v = t - HALO;              // final-stage out row pair (v, v+1)
        const bool inband = (unsigned)(v - B) < BAND;
        // MODE 1: issue weight loads before the stage chain; VALU hides them.
        Row w0, w1;
        if (MODE == 1 && inband) {
            const float4* q0 = (const float4*)(wp + (size_t)v * IMG + lane * 8);
            w0.a = q0[0]; w0.b = q0[1];
            const float4* q1 = (const float4*)(wp + (size_t)(v + 1) * IMG + lane * 8);
            w1.a = q1[0]; w1.b = q1[1];
        }
#pragma unroll
        for (int j = 0; j < NSTG; ++j)
            step2<EDGE>(x[j], mn[j], in0, in1, t - 2 * j);
        if (inband) {
            if (MODE == 0) {
                float4* q0 = (float4*)(dst + (size_t)v * IMG + lane * 8);
                q0[0] = in0.a; q0[1] = in0.b;
                float4* q1 = (float4*)(dst + (size_t)(v + 1) * IMG + lane * 8);
                q1[0] = in1.a; q1[1] = in1.b;
            } else {
                const float* p0 = (const float*)&in0;
                const float* p1 = (const float*)&in1;
                const float* q0 = (const float*)&w0;
                const float* q1 = (const float*)&w1;
#pragma unroll
                for (int i = 0; i < 8; ++i) {
                    s_prod += p0[i] * q0[i] + p1[i] * q1[i];
                    s_val += p0[i] + p1[i];
                }
            }
        }
    }
}

// ---------------- Launch 1: iterations 0..1 from y inputs ----------------
__global__ __launch_bounds__(64, 2) void skel2_first(const float* __restrict__ yp,
                                                     const float* __restrict__ yt,
                                                     float* __restrict__ dst) {
    const int blk = blockIdx.x;
    const int img = blk >> 6, band = blk & (NBAND - 1);
    const float* src = (img < NB) ? yp + (size_t)(2 * img + 1) * HW
                                  : yt + (size_t)(2 * (img - NB) + 1) * HW;
    float* d = dst + (size_t)img * HW;
    const int lane = threadIdx.x;
    const int B = band * BAND;
    float d0 = 0.f, d1 = 0.f;
    if (band == 0 || band == NBAND - 1) run<true, 0>(src, d, nullptr, B, lane, d0, d1);
    else                                run<false, 0>(src, d, nullptr, B, lane, d0, d1);
}

// ---------------- Launches 2..4: two iterations, buffer -> buffer ----------------
__global__ __launch_bounds__(64, 2) void skel2_mid(const float* __restrict__ srcb,
                                                   float* __restrict__ dstb) {
    const int blk = blockIdx.x;
    const int img = blk >> 6, band = blk & (NBAND - 1);
    const float* src = srcb + (size_t)img * HW;
    float* d = dstb + (size_t)img * HW;
    const int lane = threadIdx.x;
    const int B = band * BAND;
    float d0 = 0.f, d1 = 0.f;
    if (band == 0 || band == NBAND - 1) run<true, 0>(src, d, nullptr, B, lane, d0, d1);
    else                                run<false, 0>(src, d, nullptr, B, lane, d0, d1);
}

// ---------- Launch 5: iterations 8..9 + fused reduction (no write-out) ----------
__global__ __launch_bounds__(64, 2) void skel2_last(const float* __restrict__ srcb,
                                                    const float* __restrict__ yp,
                                                    const float* __restrict__ yt,
                                                    double* __restrict__ acc) {
    const int blk = blockIdx.x;
    const int img = blk >> 6, band = blk & (NBAND - 1);
    const float* src = srcb + (size_t)img * HW;
    // skel(pred) pairs with y_true c1; skel(true) pairs with y_pred c1.
    const float* w = (img < NB) ? yt + (size_t)(2 * img + 1) * HW
                                : yp + (size_t)(2 * (img - NB) + 1) * HW;
    const int lane = threadIdx.x;
    const int B = band * BAND;

    float s_prod = 0.f, s_val = 0.f;
    if (band == 0 || band == NBAND - 1) run<true, 1>(src, nullptr, w, B, lane, s_prod, s_val);
    else                                run<false, 1>(src, nullptr, w, B, lane, s_prod, s_val);

#pragma unroll
    for (int off = 32; off; off >>= 1) {
        s_prod += __shfl_down(s_prod, off);
        s_val += __shfl_down(s_val, off);
    }
    if (lane == 0) {
        const int base = (img < NB) ? 0 : 2;
        atomicAdd(&acc[base], (double)s_prod);
        atomicAdd(&acc[base + 1], (double)s_val);
    }
}

__global__ void finalize(const double* __restrict__ acc, float* __restrict__ out) {
    double tprec = (acc[0] + 1.0) / (acc[1] + 1.0);
    double tsens = (acc[2] + 1.0) / (acc[3] + 1.0);
    out[0] = (float)(1.0 - 2.0 * (tprec * tsens) / (tprec + tsens));
}

extern "C" void kernel_launch(void* const* d_in, const int* in_sizes, int n_in,
                              void* d_out, int out_size, void* d_ws, size_t ws_size,
                              hipStream_t stream) {
    (void)in_sizes; (void)n_in; (void)out_size; (void)ws_size;
    const float* yp = (const float*)d_in[0];
    const float* yt = (const float*)d_in[1];
    float* out = (float*)d_out;

    // Workspace: ping-pong skeleton buffers (2 x 64 MB) | acc (4 doubles)
    // (128 MB layout ran successfully in round 2 -> workspace is big enough.)
    float* bufA = (float*)d_ws;
    float* bufB = bufA + (size_t)NIMG * HW;
    double* acc = (double*)(bufB + (size_t)NIMG * HW);

    hipMemsetAsync(acc, 0, 4 * sizeof(double), stream);

    const int grid = NIMG * NBAND;  // 4096 single-wave blocks = 4 waves/SIMD allowed
    skel2_first<<<grid, 64, 0, stream>>>(yp, yt, bufA);
    skel2_mid<<<grid, 64, 0, stream>>>(bufA, bufB);
    skel2_mid<<<grid, 64, 0, stream>>>(bufB, bufA);
    skel2_mid<<<grid, 64, 0, stream>>>(bufA, bufB);
    skel2_last<<<grid, 64, 0, stream>>>(bufB, yp, yt, acc);
    finalize<<<1, 1, 0, stream>>>(acc, out);
}